// Round 7
// baseline (294.106 us; speedup 1.0000x reference)
//
#include <hip/hip_runtime.h>
#include <hip/hip_bf16.h>

typedef __hip_bfloat16 bf16;
typedef __attribute__((ext_vector_type(8))) __bf16 bf16x8;
typedef __attribute__((ext_vector_type(4))) float f32x4;

#define NB 8
#define SEQ 2048
#define CH 768
#define NH 12
#define HD 64
#define NL 32
#define BHT (NB*NH)       // 96
#define TOK (NB*SEQ)      // 16384
#define QK_SCALE 0.35355339059327379f  // 64^-0.25

// async global->LDS, 16B per lane; LDS dest = wave-uniform base + lane*16
__device__ __forceinline__ void async_ld16(const bf16* g, bf16* l) {
    unsigned loff = (unsigned)__builtin_amdgcn_readfirstlane((int)(unsigned)(uintptr_t)l);
    __builtin_amdgcn_global_load_lds(
        (const __attribute__((address_space(1))) unsigned*)(uintptr_t)g,
        (__attribute__((address_space(3))) unsigned*)(uintptr_t)loff, 16, 0, 0);
}

// ---------------- x (fp32) -> bf16, vectorized ----------------
__global__ void convert_x(const float* __restrict__ x, bf16* __restrict__ xb) {
    size_t i = ((size_t)blockIdx.x * 256 + threadIdx.x) * 8;
    float4 a = *reinterpret_cast<const float4*>(x + i);
    float4 b = *reinterpret_cast<const float4*>(x + i + 4);
    alignas(16) bf16 tmp[8];
    tmp[0] = __float2bfloat16(a.x); tmp[1] = __float2bfloat16(a.y);
    tmp[2] = __float2bfloat16(a.z); tmp[3] = __float2bfloat16(a.w);
    tmp[4] = __float2bfloat16(b.x); tmp[5] = __float2bfloat16(b.y);
    tmp[6] = __float2bfloat16(b.z); tmp[7] = __float2bfloat16(b.w);
    *reinterpret_cast<uint4*>(xb + i) = *reinterpret_cast<const uint4*>(tmp);
}

// ---------------- transpose (fp32 in, bf16 out), H x W -> W x H ----------------
__global__ void transpose_f32(const float* __restrict__ in, bf16* __restrict__ outp,
                              int Hrows, int Wcols) {
    __shared__ float tile[32][33];
    int bx = blockIdx.x * 32, by = blockIdx.y * 32;
    int tx = threadIdx.x, ty = threadIdx.y; // 32 x 8
    for (int i = 0; i < 32; i += 8)
        tile[ty + i][tx] = in[(size_t)(by + ty + i) * Wcols + bx + tx];
    __syncthreads();
    for (int i = 0; i < 32; i += 8)
        outp[(size_t)(bx + ty + i) * Hrows + by + tx] = __float2bfloat16(tile[tx][ty + i]);
}

// ---------------- GEMM: C[M][N] = A[M][K] * Bt[N][K]^T ----------------
// 128x128 tile, BK=32, 4 waves (2x2), global_load_lds width-16 staging (m97).
// EPI=0: Q/K row-major scaled + fused landmark means; V -> V^T via LDS
//        transpose with coalesced 256B row stores.
// EPI=1: out[row][col] = acc + bias[col], fp32 store.
template <int EPI>
__global__ __launch_bounds__(256) void gemm_bt(
    const bf16* __restrict__ A, const bf16* __restrict__ Bt,
    int Nout, int Kdim,
    bf16* __restrict__ q, bf16* __restrict__ k, bf16* __restrict__ vt,
    float* __restrict__ Ql, float* __restrict__ Kl,
    float* __restrict__ outp, const float* __restrict__ bias_f) {
    __shared__ __align__(16) char smem[EPI == 0 ? 34816 : 16384];
    bf16* As = (bf16*)smem;                 // 128*32 bf16 = 8192 B
    bf16* Bs = (bf16*)(smem + 8192);        // 8192 B
    const int t = threadIdx.x;
    const int wave = t >> 6, lane = t & 63;
    const int quad = lane >> 4, l15 = lane & 15;
    const int wr = wave >> 1, wc = wave & 1;
    const int bm0 = blockIdx.y * 128;
    const int bn0 = blockIdx.x * 128;

    f32x4 acc[4][4];
    const f32x4 zero4 = {0.f, 0.f, 0.f, 0.f};
    for (int i = 0; i < 4; i++)
        for (int jj = 0; jj < 4; jj++) acc[i][jj] = zero4;

    for (int k0 = 0; k0 < Kdim; k0 += 32) {
        __syncthreads();
        #pragma unroll
        for (int r = 0; r < 2; r++) {
            int c = t + r * 256;       // 0..511; LDS byte offset = c*16
            int row = c >> 2;          // 0..127
            int col = (c & 3) * 8;     // 0,8,16,24
            async_ld16(&A[(size_t)(bm0 + row) * Kdim + k0 + col], &As[(wave * 64 + r * 256) * 8]);
            async_ld16(&Bt[(size_t)(bn0 + row) * Kdim + k0 + col], &Bs[(wave * 64 + r * 256) * 8]);
        }
        __syncthreads();
        bf16x8 af[4], bfr[4];
        #pragma unroll
        for (int mi = 0; mi < 4; mi++)
            af[mi] = *reinterpret_cast<const bf16x8*>(&As[(wr * 64 + mi * 16 + l15) * 32 + quad * 8]);
        #pragma unroll
        for (int ni = 0; ni < 4; ni++)
            bfr[ni] = *reinterpret_cast<const bf16x8*>(&Bs[(wc * 64 + ni * 16 + l15) * 32 + quad * 8]);
        #pragma unroll
        for (int mi = 0; mi < 4; mi++)
            #pragma unroll
            for (int ni = 0; ni < 4; ni++)
                acc[mi][ni] = __builtin_amdgcn_mfma_f32_16x16x32_bf16(af[mi], bfr[ni], acc[mi][ni], 0, 0, 0);
    }

    if (EPI == 0) {
        // 768 % 128 == 0: the N-tile lies entirely within Q, K, or V.
        const int which = bn0 / CH;                      // block-uniform
        const int b = bm0 >> 11;                         // block-uniform
        const int nstart = bm0 & 2047;
        if (which < 2) {
            bf16* dstqk = (which == 0) ? q : k;
            float* dstl = (which == 0) ? Ql : Kl;
            const int rem0 = bn0 - which * CH + wc * 64;
            const int nnb = nstart + wr * 64;
            const int l = nnb >> 6;                      // landmark owned by this wave
            #pragma unroll
            for (int ni = 0; ni < 4; ni++) {
                int rem = rem0 + ni * 16 + l15;
                int h = rem >> 6, dd = rem & 63;
                int bh = b * NH + h;
                float colsum = 0.f;
                #pragma unroll
                for (int mi = 0; mi < 4; mi++) {
                    int nn0 = nnb + mi * 16 + quad * 4;
                    #pragma unroll
                    for (int r = 0; r < 4; r++) {
                        float val = acc[mi][ni][r];
                        colsum += val;
                        dstqk[((size_t)bh * SEQ + nn0 + r) * HD + dd] = __float2bfloat16(val * QK_SCALE);
                    }
                }
                colsum += __shfl_xor(colsum, 16);
                colsum += __shfl_xor(colsum, 32);
                if (quad == 0)
                    dstl[((size_t)bh * NL + l) * HD + dd] = colsum * (QK_SCALE / 64.f);
            }
        } else {
            // V^T: transpose the 128x128 tile through LDS, then coalesced stores.
            __syncthreads();                             // staging bufs dead now
            bf16* VT = (bf16*)smem;                      // [colL][n], stride 136
            #pragma unroll
            for (int ni = 0; ni < 4; ni++) {
                int colL = wc * 64 + ni * 16 + l15;
                #pragma unroll
                for (int mi = 0; mi < 4; mi++) {
                    int nn = wr * 64 + mi * 16 + quad * 4;
                    alignas(8) bf16 four[4];
                    #pragma unroll
                    for (int r = 0; r < 4; r++) four[r] = __float2bfloat16(acc[mi][ni][r]);
                    *reinterpret_cast<uint2*>(&VT[colL * 136 + nn]) =
                        *reinterpret_cast<const uint2*>(four);
                }
            }
            __syncthreads();
            const int rem0c = bn0 - 2 * CH;              // multiple of 128
            #pragma unroll
            for (int pass = 0; pass < 8; pass++) {
                int rowL = (t >> 4) + pass * 16;         // 0..127
                int h = (rem0c + rowL) >> 6, dd = rowL & 63;
                int bh = b * NH + h;
                int off = (t & 15) * 8;                  // element offset, 16B chunks
                uint4 val = *reinterpret_cast<const uint4*>(&VT[rowL * 136 + off]);
                *reinterpret_cast<uint4*>(&vt[((size_t)bh * HD + dd) * SEQ + nstart + off]) = val;
            }
        }
    } else {
        #pragma unroll
        for (int mi = 0; mi < 4; mi++)
            #pragma unroll
            for (int ni = 0; ni < 4; ni++) {
                int col = bn0 + wc * 64 + ni * 16 + l15;
                #pragma unroll
                for (int r = 0; r < 4; r++) {
                    int row = bm0 + wr * 64 + mi * 16 + quad * 4 + r;
                    outp[(size_t)row * Nout + col] = acc[mi][ni][r] + bias_f[col];
                }
            }
    }
}

// ---------------- kernel_3 softmax + @V via MFMA, 4 blocks/bh, partials ----------------
__global__ __launch_bounds__(256) void k3_pv(const float* __restrict__ Ql,
                                             const bf16* __restrict__ Kb,
                                             const bf16* __restrict__ Vt,
                                             float* __restrict__ Opart,
                                             float* __restrict__ Spart) {
    __shared__ __align__(16) bf16 Pw[4][32 * 136];
    __shared__ __align__(16) float Ored[4][32 * 65];
    __shared__ float Sred[4 * 32];
    const int bh = blockIdx.x, cc = blockIdx.y;
    const int n0 = cc * 512;
    const int t = threadIdx.x;
    const int w = t >> 6, lane = t & 63;
    const int quad = lane >> 4, l15 = lane & 15;

    const bf16* Kbh = Kb + (size_t)bh * SEQ * HD;
    const bf16* Vtb = Vt + (size_t)bh * HD * SEQ;

    bf16x8 af[2][2];
    #pragma unroll
    for (int mt = 0; mt < 2; mt++)
        #pragma unroll
        for (int kh = 0; kh < 2; kh++) {
            const float* src = Ql + (size_t)bh * NL * HD + (mt * 16 + l15) * 64 + kh * 32 + quad * 8;
            alignas(16) bf16 tmp[8];
            #pragma unroll
            for (int jj = 0; jj < 8; jj++) tmp[jj] = __float2bfloat16(src[jj]);
            af[mt][kh] = *reinterpret_cast<const bf16x8*>(tmp);
        }

    const f32x4 zero4 = {0.f, 0.f, 0.f, 0.f};
    f32x4 oacc[2][4];
    #pragma unroll
    for (int mt = 0; mt < 2; mt++)
        #pragma unroll
        for (int nd = 0; nd < 4; nd++) oacc[mt][nd] = zero4;
    float rs[2][4];
    #pragma unroll
    for (int mt = 0; mt < 2; mt++)
        #pragma unroll
        for (int r = 0; r < 4; r++) rs[mt][r] = 0.f;

    bf16* Pme = &Pw[w][0];

    #pragma unroll
    for (int h = 0; h < 2; h++) {
        f32x4 sacc[2][4];
        #pragma unroll
        for (int mt = 0; mt < 2; mt++)
            #pragma unroll
            for (int nt = 0; nt < 4; nt++) sacc[mt][nt] = zero4;
        #pragma unroll
        for (int nt = 0; nt < 4; nt++) {
            int n = n0 + w * 128 + h * 64 + nt * 16 + l15;
            bf16x8 kf0 = *reinterpret_cast<const bf16x8*>(&Kbh[(size_t)n * HD + quad * 8]);
            bf16x8 kf1 = *reinterpret_cast<const bf16x8*>(&Kbh[(size_t)n * HD + 32 + quad * 8]);
            #pragma unroll
            for (int mt = 0; mt < 2; mt++) {
                sacc[mt][nt] = __builtin_amdgcn_mfma_f32_16x16x32_bf16(af[mt][0], kf0, sacc[mt][nt], 0, 0, 0);
                sacc[mt][nt] = __builtin_amdgcn_mfma_f32_16x16x32_bf16(af[mt][1], kf1, sacc[mt][nt], 0, 0, 0);
            }
        }
        #pragma unroll
        for (int mt = 0; mt < 2; mt++)
            #pragma unroll
            for (int nt = 0; nt < 4; nt++)
                #pragma unroll
                for (int r = 0; r < 4; r++) {
                    float pv = __expf(sacc[mt][nt][r]);
                    rs[mt][r] += pv;
                    int row = mt * 16 + quad * 4 + r;
                    Pme[row * 136 + h * 64 + nt * 16 + l15] = __float2bfloat16(pv);
                }
    }
    __asm__ __volatile__("s_waitcnt lgkmcnt(0)" ::: "memory");

    #pragma unroll
    for (int kt = 0; kt < 4; kt++) {
        bf16x8 pa[2];
        pa[0] = *reinterpret_cast<const bf16x8*>(&Pme[l15 * 136 + kt * 32 + quad * 8]);
        pa[1] = *reinterpret_cast<const bf16x8*>(&Pme[(16 + l15) * 136 + kt * 32 + quad * 8]);
        int kbase = n0 + w * 128 + kt * 32 + quad * 8;
        #pragma unroll
        for (int nd = 0; nd < 4; nd++) {
            bf16x8 bv = *reinterpret_cast<const bf16x8*>(&Vtb[(size_t)(nd * 16 + l15) * SEQ + kbase]);
            oacc[0][nd] = __builtin_amdgcn_mfma_f32_16x16x32_bf16(pa[0], bv, oacc[0][nd], 0, 0, 0);
            oacc[1][nd] = __builtin_amdgcn_mfma_f32_16x16x32_bf16(pa[1], bv, oacc[1][nd], 0, 0, 0);
        }
    }

    #pragma unroll
    for (int mt = 0; mt < 2; mt++)
        #pragma unroll
        for (int r = 0; r < 4; r++) {
            float v = rs[mt][r];
            #pragma unroll
            for (int o = 1; o < 16; o <<= 1) v += __shfl_xor(v, o);
            rs[mt][r] = v;
        }
    if (l15 == 0)
        #pragma unroll
        for (int mt = 0; mt < 2; mt++)
            #pragma unroll
            for (int r = 0; r < 4; r++)
                Sred[w * 32 + mt * 16 + quad * 4 + r] = rs[mt][r];
    #pragma unroll
    for (int mt = 0; mt < 2; mt++)
        #pragma unroll
        for (int nd = 0; nd < 4; nd++)
            #pragma unroll
            for (int r = 0; r < 4; r++)
                Ored[w][(mt * 16 + quad * 4 + r) * 65 + nd * 16 + l15] = oacc[mt][nd][r];
    __syncthreads();

    float* Op = Opart + ((size_t)bh * 4 + cc) * (NL * HD);
    for (int e = t; e < 2048; e += 256) {
        int m = e >> 6, dd = e & 63;
        Op[e] = Ored[0][m * 65 + dd] + Ored[1][m * 65 + dd] +
                Ored[2][m * 65 + dd] + Ored[3][m * 65 + dd];
    }
    if (t < 32)
        Spart[((size_t)bh * 4 + cc) * NL + t] = Sred[t] + Sred[32 + t] + Sred[64 + t] + Sred[96 + t];
}

// ---------------- kernel_2 softmax + Newton-Schulz + W2 = inv2 @ k3v ----------------
__device__ inline void mm32(float* Cm, const float* Am, const float* Bm, int t) {
    for (int e = t; e < 1024; e += 256) {
        int i = e >> 5, jj = e & 31;
        float s = 0.f;
        #pragma unroll
        for (int kk = 0; kk < 32; kk++) s += Am[i * 32 + kk] * Bm[kk * 32 + jj];
        Cm[e] = s;
    }
}

__global__ __launch_bounds__(256) void newton_inv(const float* __restrict__ Ql,
                                                  const float* __restrict__ Kl,
                                                  const float* __restrict__ Opart,
                                                  const float* __restrict__ Spart,
                                                  float* __restrict__ W2) {
    __shared__ float K2[1024], Vv[1024], KV[1024], Ta[1024], Tb[1024];
    __shared__ float K3[2048];
    __shared__ float stot[32];
    __shared__ float red[32];
    __shared__ float denom_s;
    int bh = blockIdx.x;
    int t = threadIdx.x;
    const float* ql = Ql + (size_t)bh * NL * HD;
    const float* kl = Kl + (size_t)bh * NL * HD;

    if (t < 32) {
        const float* sp = Spart + (size_t)bh * 4 * NL;
        stot[t] = sp[t] + sp[32 + t] + sp[64 + t] + sp[96 + t];
    }
    {
        const float* op = Opart + (size_t)bh * 4 * (NL * HD);
        for (int e = t; e < 2048; e += 256)
            K3[e] = op[e] + op[2048 + e] + op[4096 + e] + op[6144 + e];
    }

    for (int e = t; e < 1024; e += 256) {
        int i = e >> 5, jj = e & 31;
        float s = 0.f;
        #pragma unroll 8
        for (int d = 0; d < 64; d++) s += ql[i * 64 + d] * kl[jj * 64 + d];
        K2[e] = s;
    }
    __syncthreads();
    for (int e = t; e < 2048; e += 256) K3[e] *= (1.f / stot[e >> 6]);
    if (t < 32) {
        float mx = -1e30f;
        for (int jj = 0; jj < 32; jj++) mx = fmaxf(mx, K2[t * 32 + jj]);
        float sm = 0.f;
        for (int jj = 0; jj < 32; jj++) { float e = __expf(K2[t * 32 + jj] - mx); K2[t * 32 + jj] = e; sm += e; }
        float inv = 1.f / sm;
        for (int jj = 0; jj < 32; jj++) K2[t * 32 + jj] *= inv;
    }
    __syncthreads();
    if (t < 32) {
        float cs = 0.f;
        for (int i = 0; i < 32; i++) cs += K2[i * 32 + t];
        red[t] = cs;
    }
    __syncthreads();
    if (t == 0) {
        float mx = red[0];
        for (int jj = 1; jj < 32; jj++) mx = fmaxf(mx, red[jj]);
        denom_s = mx;
    }
    __syncthreads();
    float invden = 1.f / denom_s;
    for (int e = t; e < 1024; e += 256) {
        int i = e >> 5, jj = e & 31;
        Vv[e] = K2[jj * 32 + i] * invden;
    }
    __syncthreads();
    for (int it = 0; it < 6; it++) {
        mm32(KV, K2, Vv, t);
        __syncthreads();
        for (int e = t; e < 1024; e += 256) { int i = e >> 5, jj = e & 31; Ta[e] = ((i == jj) ? 7.f : 0.f) - KV[e]; }
        __syncthreads();
        mm32(Tb, KV, Ta, t);
        __syncthreads();
        for (int e = t; e < 1024; e += 256) { int i = e >> 5, jj = e & 31; Tb[e] = ((i == jj) ? 15.f : 0.f) - Tb[e]; }
        __syncthreads();
        mm32(Ta, KV, Tb, t);
        __syncthreads();
        for (int e = t; e < 1024; e += 256) { int i = e >> 5, jj = e & 31; Ta[e] = ((i == jj) ? 13.f : 0.f) - Ta[e]; }
        __syncthreads();
        mm32(Tb, Vv, Ta, t);
        __syncthreads();
        for (int e = t; e < 1024; e += 256) Vv[e] = 0.25f * Tb[e];
        __syncthreads();
    }
    for (int e = t; e < 2048; e += 256) {
        int i = e >> 6, dd = e & 63;
        float s = 0.f;
        #pragma unroll
        for (int kk = 0; kk < 32; kk++) s += Vv[i * 32 + kk] * K3[kk * 64 + dd];
        W2[(size_t)bh * NL * HD + e] = s;
    }
}

// ---------------- fused: Xp = softmax(Q Kl^T) @ W2 via MFMA ----------------
__global__ __launch_bounds__(256) void rows_fused(const bf16* __restrict__ Qb,
                                                  const float* __restrict__ Kl,
                                                  const float* __restrict__ W2,
                                                  bf16* __restrict__ Xp) {
    __shared__ __align__(16) bf16 Klb[32 * 64];
    __shared__ __align__(16) bf16 W2t[64 * 32];
    __shared__ __align__(16) bf16 Pw[4][32 * 40];
    const int bh = blockIdx.x, tile = blockIdx.y;
    const int t = threadIdx.x, w = t >> 6, lane = t & 63;
    const int quad = lane >> 4, l15 = lane & 15;

    {
        const float* ksrc = Kl + (size_t)bh * NL * HD;
        const float* wsrc = W2 + (size_t)bh * NL * HD;
        int e0 = t * 8;
        #pragma unroll
        for (int jj = 0; jj < 8; jj++) {
            int e = e0 + jj;
            Klb[e] = __float2bfloat16(ksrc[e]);
            int kk = e >> 6, dd = e & 63;
            W2t[dd * 32 + kk] = __float2bfloat16(wsrc[e]);
        }
    }
    __syncthreads();

    const int b = bh / NH, h = bh - b * NH;
    const int row0 = tile * 128 + w * 32;
    const bf16* qbase = Qb + ((size_t)bh * SEQ + row0) * HD;

    const f32x4 zero4 = {0.f, 0.f, 0.f, 0.f};
    f32x4 sacc[2][2];
    #pragma unroll
    for (int mt = 0; mt < 2; mt++)
        #pragma unroll
        for (int nt = 0; nt < 2; nt++) sacc[mt][nt] = zero4;
    #pragma unroll
    for (int kh = 0; kh < 2; kh++) {
        bf16x8 bk0 = *reinterpret_cast<const bf16x8*>(&Klb[(l15) * 64 + kh * 32 + quad * 8]);
        bf16x8 bk1 = *reinterpret_cast<const bf16x8*>(&Klb[(16 + l15) * 64 + kh * 32 + quad * 8]);
        #pragma unroll
        for (int mt = 0; mt < 2; mt++) {
            bf16x8 aq = *reinterpret_cast<const bf16x8*>(&qbase[(size_t)(mt * 16 + l15) * HD + kh * 32 + quad * 8]);
            sacc[mt][0] = __builtin_amdgcn_mfma_f32_16x16x32_bf16(aq, bk0, sacc[mt][0], 0, 0, 0);
            sacc[mt][1] = __builtin_amdgcn_mfma_f32_16x16x32_bf16(aq, bk1, sacc[mt][1], 0, 0, 0);
        }
    }

    float invs[2][4];
    bf16* Pme = &Pw[w][0];
    #pragma unroll
    for (int mt = 0; mt < 2; mt++)
        #pragma unroll
        for (int r = 0; r < 4; r++) {
            float v0 = __expf(sacc[mt][0][r]);
            float v1 = __expf(sacc[mt][1][r]);
            int row = mt * 16 + quad * 4 + r;
            Pme[row * 40 + l15] = __float2bfloat16(v0);
            Pme[row * 40 + 16 + l15] = __float2bfloat16(v1);
            float v = v0 + v1;
            #pragma unroll
            for (int o = 1; o < 16; o <<= 1) v += __shfl_xor(v, o);
            invs[mt][r] = 1.f / v;
        }
    __asm__ __volatile__("s_waitcnt lgkmcnt(0)" ::: "memory");

    f32x4 oacc[2][4];
    #pragma unroll
    for (int mt = 0; mt < 2; mt++)
        #pragma unroll
        for (int nd = 0; nd < 4; nd++) oacc[mt][nd] = zero4;
    bf16x8 pa[2];
    pa[0] = *reinterpret_cast<const bf16x8*>(&Pme[l15 * 40 + quad * 8]);
    pa[1] = *reinterpret_cast<const bf16x8*>(&Pme[(16 + l15) * 40 + quad * 8]);
    #pragma unroll
    for (int nd = 0; nd < 4; nd++) {
        bf16x8 bw = *reinterpret_cast<const bf16x8*>(&W2t[(nd * 16 + l15) * 32 + quad * 8]);
        oacc[0][nd] = __builtin_amdgcn_mfma_f32_16x16x32_bf16(pa[0], bw, oacc[0][nd], 0, 0, 0);
        oacc[1][nd] = __builtin_amdgcn_mfma_f32_16x16x32_bf16(pa[1], bw, oacc[1][nd], 0, 0, 0);
    }

    #pragma unroll
    for (int mt = 0; mt < 2; mt++)
        #pragma unroll
        for (int nd = 0; nd < 4; nd++)
            #pragma unroll
            for (int r = 0; r < 4; r++) {
                int row = row0 + mt * 16 + quad * 4 + r;
                Xp[((size_t)(b * SEQ + row)) * CH + h * 64 + nd * 16 + l15] =
                    __float2bfloat16(oacc[mt][nd][r] * invs[mt][r]);
            }
}

extern "C" void kernel_launch(void* const* d_in, const int* in_sizes, int n_in,
                              void* d_out, int out_size, void* d_ws, size_t ws_size,
                              hipStream_t stream) {
    const float* x      = (const float*)d_in[0];
    const float* w_qkv  = (const float*)d_in[1];
    const float* w_proj = (const float*)d_in[2];
    const float* b_proj = (const float*)d_in[3];
    float* out = (float*)d_out;

    char* ws = (char*)d_ws;
    size_t off = 0;
    auto alloc = [&](size_t bytes) -> void* {
        void* p = ws + off;
        off += (bytes + 255) & ~(size_t)255;
        return p;
    };
    bf16* wqkvT  = (bf16*)alloc((size_t)3 * CH * CH * 2);
    bf16* wprojT = (bf16*)alloc((size_t)CH * CH * 2);
    bf16* Qb     = (bf16*)alloc((size_t)BHT * SEQ * HD * 2);
    bf16* Kb     = (bf16*)alloc((size_t)BHT * SEQ * HD * 2);
    bf16* Vt     = (bf16*)alloc((size_t)BHT * SEQ * HD * 2);
    float* Ql    = (float*)alloc((size_t)BHT * NL * HD * 4);
    float* Kl    = (float*)alloc((size_t)BHT * NL * HD * 4);
    float* Opart = (float*)alloc((size_t)BHT * 4 * NL * HD * 4);
    float* Spart = (float*)alloc((size_t)BHT * 4 * NL * 4);
    float* W2    = (float*)alloc((size_t)BHT * NL * HD * 4);
    bf16* Xp     = (bf16*)alloc((size_t)TOK * CH * 2);  // aliased: xb before rows_fused
    if (ws_size < off) return;
    bf16* xb = Xp;

    convert_x<<<TOK * CH / 2048, 256, 0, stream>>>(x, xb);
    transpose_f32<<<dim3((3 * CH) / 32, CH / 32), dim3(32, 8), 0, stream>>>(w_qkv, wqkvT, CH, 3 * CH);
    transpose_f32<<<dim3(CH / 32, CH / 32), dim3(32, 8), 0, stream>>>(w_proj, wprojT, CH, CH);

    gemm_bt<0><<<dim3((3 * CH) / 128, TOK / 128), 256, 0, stream>>>(
        xb, wqkvT, 3 * CH, CH, Qb, Kb, Vt, Ql, Kl, nullptr, nullptr);

    k3_pv<<<dim3(BHT, 4), 256, 0, stream>>>(Ql, Kb, Vt, Opart, Spart);
    newton_inv<<<BHT, 256, 0, stream>>>(Ql, Kl, Opart, Spart, W2);
    rows_fused<<<dim3(BHT, SEQ / 128), 256, 0, stream>>>(Qb, Kl, W2, Xp);

    gemm_bt<1><<<dim3(CH / 128, TOK / 128), 256, 0, stream>>>(
        Xp, wprojT, CH, CH, nullptr, nullptr, nullptr, nullptr, nullptr, out, b_proj);
}